// Round 12
// baseline (124.046 us; speedup 1.0000x reference)
//
#include <hip/hip_runtime.h>

// Binarized conv block via i8 MFMA implicit GEMM.
//   a = sign(x+bias1) in {+1,-1} (i8), zero-padded image [32][58][58][256] i8
//   qk = sign(kernel) in {+1,-1} (i8), pre-transposed to W_t[co][k]
//   conv == GEMM: C[pixel][co] = sum_k A_im2col[pixel][k] * W[k][co]
//   out = relu(C*scale[co] + shift[co])   (folded BN + bias2)
// i8 zero-pad == true conv zero-pad -> exact integers, no edge corrections.
//
// R11 (8-phase, 3-deep, BM128xBN256, 72KB LDS) hit 90us / 27% MfmaUtil at
// ~16% occupancy: <=2 blocks/CU leaves nothing to hide ds_read latency +
// barrier sync under. R12: BM=128 x BN=128, 16KB/buffer, 3-deep = 48KB ->
// 3 blocks/CU (12 waves/CU of cross-block overlap, the m97/m114 regime) +
// 1568 blocks for dynamic balance. Counted vmcnt(4) steady-state (one stage
// in flight), phases split {A-reads+A-stage | MFMA} / {A-reads+B-stage | MFMA}.

typedef int v4i __attribute__((ext_vector_type(4)));
typedef unsigned int u32;

#define NB   32
#define HW   56
#define HP   58
#define HP2  (HP*HP)             // 3364
#define CIN  256
#define COUT 256
#define NPIX (NB*HW*HW)          // 100352
#define KTOT 2304
#define BM   128                 // pixels per block
#define BN   128                 // couts per block
#define NSTEP 36                 // K steps of 64

#define PA_BYTES ((size_t)NB*HP*HP*CIN)     // 27,557,888
#define WT_OFF   PA_BYTES
#define WT_BYTES ((size_t)KTOT*COUT)        // 589,824
#define SC_OFF   (WT_OFF + WT_BYTES)
#define SH_OFF   (SC_OFF + 1024)

__device__ __forceinline__ void g2l16(const void* g, void* l) {
    __builtin_amdgcn_global_load_lds(
        (const __attribute__((address_space(1))) void*)g,
        (__attribute__((address_space(3))) void*)l, 16, 0, 0);
}

// ------- pack activations incl. pad ring: sign(x+bias1) or 0 -> i8 -------
__global__ __launch_bounds__(256) void pack_a_kernel(
    const float* __restrict__ x, const float* __restrict__ b1,
    signed char* __restrict__ pa)
{
    const int lane = threadIdx.x & 63;
    const int pp = blockIdx.x * 4 + (threadIdx.x >> 6);   // padded pixel
    const int n = pp / HP2, r = pp % HP2, ph = r / HP, pw = r % HP;
    const int ci = lane * 4;
    u32 o = 0;
    if (ph >= 1 && ph <= HW && pw >= 1 && pw <= HW) {     // wave-uniform branch
        const int pix = (n * HW + ph - 1) * HW + (pw - 1);
        const float4 xv = *(const float4*)(x + (size_t)pix * CIN + ci);
        const float4 bv = *(const float4*)(b1 + ci);
        o  = (u32)(unsigned char)((xv.x + bv.x >= 0.f) ? 1 : -1);
        o |= (u32)(unsigned char)((xv.y + bv.y >= 0.f) ? 1 : -1) << 8;
        o |= (u32)(unsigned char)((xv.z + bv.z >= 0.f) ? 1 : -1) << 16;
        o |= (u32)(unsigned char)((xv.w + bv.w >= 0.f) ? 1 : -1) << 24;
    }
    *(u32*)(pa + (size_t)pp * CIN + ci) = o;
    // grid = NB*HP*HP/4 = 26912
}

// ---------------- pack + transpose weights: W_t[co][k] i8 ----------------
__global__ __launch_bounds__(256) void packw_kernel(
    const float* __restrict__ k, signed char* __restrict__ wt)
{
    __shared__ signed char tile[64][256];
    const int t = threadIdx.x, k0 = blockIdx.x * 64;
    for (int j = 0; j < 64; ++j)
        tile[j][t] = (k[(size_t)(k0 + j) * COUT + t] >= 0.f) ? 1 : -1;
    __syncthreads();
    u32 wd[16];
#pragma unroll
    for (int j = 0; j < 16; ++j) wd[j] = 0;
#pragma unroll
    for (int j = 0; j < 64; ++j)
        wd[j >> 2] |= ((u32)(unsigned char)tile[j][t]) << ((j & 3) * 8);
    uint4* dst = (uint4*)(wt + (size_t)t * KTOT + k0);
#pragma unroll
    for (int j = 0; j < 4; ++j)
        dst[j] = make_uint4(wd[4*j], wd[4*j+1], wd[4*j+2], wd[4*j+3]);
    // grid = KTOT/64 = 36
}

// ---------------- fold BN + bias2 ----------------
__global__ __launch_bounds__(256) void bnprep_kernel(
    const float* __restrict__ beta, const float* __restrict__ mean,
    const float* __restrict__ var, const float* __restrict__ b2,
    float* __restrict__ scale, float* __restrict__ shift)
{
    const int t = threadIdx.x;
    const float s = rsqrtf(var[t] + 1e-3f);
    scale[t] = s;
    shift[t] = beta[t] - mean[t] * s + b2[t];
}

// ---------------- i8 implicit-GEMM conv + BN + relu ----------------
// 256 thr (4 waves); block = 128 pixels x 128 couts; wave v owns all 128
// pixels x couts [v*32, v*32+32): acc[8][2], 16 mfma per K-step.
__global__ __launch_bounds__(256, 3) void conv_mfma_kernel(
    const signed char* __restrict__ pa, const signed char* __restrict__ wt,
    const float* __restrict__ scale, const float* __restrict__ shift,
    float* __restrict__ out)
{
    __shared__ signed char Al[3][BM * 64];     // 3 x 8 KB
    __shared__ signed char Bl[3][BN * 64];     // 3 x 8 KB

    const int t = threadIdx.x, l = t & 63, v = t >> 6;
    const int tile = blockIdx.x >> 1;
    const int co0  = (blockIdx.x & 1) << 7;    // 0 or 128
    const int p0 = tile * BM;

    // A staging: thread t stages chunk (t&3) of pixels q and q+64 (q = t>>2)
    const signed char* abase[2];
#pragma unroll
    for (int i = 0; i < 2; ++i) {
        const int q = (t >> 2) + i * 64;
        const int p = p0 + q;
        const int n = p / 3136, r = p % 3136, h = r / 56, w = r % 56;
        const int aswz = (((t & 3) ^ ((q >> 1) & 3)) << 4);  // source pre-swizzle
        abase[i] = pa + ((size_t)(n * HP + h) * HP + w) * CIN + aswz;
    }

    // B staging: call j stages LDS row r = v*32 + j*16 + l/4, chunk l&3
    const signed char* wbase[2];
#pragma unroll
    for (int j = 0; j < 2; ++j) {
        const int r = v * 32 + j * 16 + (l >> 2);
        const int bswz = (((l & 3) ^ ((r >> 1) & 3)) << 4);
        wbase[j] = wt + (size_t)(co0 + r) * KTOT + bswz;
    }

    // fragment ds_read byte offsets (swizzled reads match pre-swizzled src)
    int aoff[8], boff[2];
#pragma unroll
    for (int pg = 0; pg < 8; ++pg) {
        const int row = pg * 16 + (l & 15);
        aoff[pg] = row * 64 + ((((l >> 4) ^ (row >> 1)) & 3) << 4);
    }
#pragma unroll
    for (int cg = 0; cg < 2; ++cg) {
        const int row = v * 32 + cg * 16 + (l & 15);
        boff[cg] = row * 64 + ((((l >> 4) ^ (row >> 1)) & 3) << 4);
    }

    v4i acc[8][2];
#pragma unroll
    for (int i = 0; i < 8; ++i)
#pragma unroll
        for (int j = 0; j < 2; ++j) acc[i][j] = (v4i){0, 0, 0, 0};

    auto goffA = [&](int s) {
        const int tap = s >> 2, cq = s & 3;
        const int ty = tap / 3, tx = tap - ty * 3;
        return ((ty * HP + tx) << 8) + (cq << 6);
    };
    auto STAGE_A = [&](int buf, int s) {       // 2 vm-items per wave
        const int go = goffA(s);
        g2l16(abase[0] + go, &Al[buf][v * 1024]);
        g2l16(abase[1] + go, &Al[buf][4096 + v * 1024]);
    };
    auto STAGE_B = [&](int buf, int s) {       // 2 vm-items per wave
        g2l16(wbase[0] + (s << 6), &Bl[buf][v * 2048]);
        g2l16(wbase[1] + (s << 6), &Bl[buf][v * 2048 + 1024]);
    };

    // prologue: 2 stages in flight (8 items), wait stage0 (allow stage1's 4)
    STAGE_A(0, 0); STAGE_B(0, 0);
    STAGE_A(1, 1); STAGE_B(1, 1);
    asm volatile("s_waitcnt vmcnt(4)" ::: "memory");
    __builtin_amdgcn_s_barrier();

    int cur = 0;
#pragma unroll 1
    for (int s = 0; s < NSTEP; ++s) {
        signed char* Ac = &Al[0][0] + cur * (BM * 64);
        signed char* Bc = &Bl[0][0] + cur * (BN * 64);
        const int stg = (cur >= 1) ? cur - 1 : 2;        // (cur+2)%3
        const bool do_stage = (s + 2 < NSTEP);

        // ---- phase 0: A-reads pg0-3 + B-reads + A-stage; MFMA half 0 ----
        v4i af0 = *(const v4i*)(Ac + aoff[0]);
        v4i af1 = *(const v4i*)(Ac + aoff[1]);
        v4i af2 = *(const v4i*)(Ac + aoff[2]);
        v4i af3 = *(const v4i*)(Ac + aoff[3]);
        v4i bf0 = *(const v4i*)(Bc + boff[0]);
        v4i bf1 = *(const v4i*)(Bc + boff[1]);
        if (do_stage) STAGE_A(stg, s + 2);
        asm volatile("" ::: "memory");
        __builtin_amdgcn_s_barrier();
        __builtin_amdgcn_s_setprio(1);
        acc[0][0] = __builtin_amdgcn_mfma_i32_16x16x64_i8(af0, bf0, acc[0][0], 0, 0, 0);
        acc[0][1] = __builtin_amdgcn_mfma_i32_16x16x64_i8(af0, bf1, acc[0][1], 0, 0, 0);
        acc[1][0] = __builtin_amdgcn_mfma_i32_16x16x64_i8(af1, bf0, acc[1][0], 0, 0, 0);
        acc[1][1] = __builtin_amdgcn_mfma_i32_16x16x64_i8(af1, bf1, acc[1][1], 0, 0, 0);
        acc[2][0] = __builtin_amdgcn_mfma_i32_16x16x64_i8(af2, bf0, acc[2][0], 0, 0, 0);
        acc[2][1] = __builtin_amdgcn_mfma_i32_16x16x64_i8(af2, bf1, acc[2][1], 0, 0, 0);
        acc[3][0] = __builtin_amdgcn_mfma_i32_16x16x64_i8(af3, bf0, acc[3][0], 0, 0, 0);
        acc[3][1] = __builtin_amdgcn_mfma_i32_16x16x64_i8(af3, bf1, acc[3][1], 0, 0, 0);
        __builtin_amdgcn_s_setprio(0);
        asm volatile("" ::: "memory");
        __builtin_amdgcn_s_barrier();

        // ---- phase 1: A-reads pg4-7 + B-stage; MFMA half 1 ----
        v4i af4 = *(const v4i*)(Ac + aoff[4]);
        v4i af5 = *(const v4i*)(Ac + aoff[5]);
        v4i af6 = *(const v4i*)(Ac + aoff[6]);
        v4i af7 = *(const v4i*)(Ac + aoff[7]);
        if (do_stage) STAGE_B(stg, s + 2);
        asm volatile("" ::: "memory");
        __builtin_amdgcn_s_barrier();
        __builtin_amdgcn_s_setprio(1);
        acc[4][0] = __builtin_amdgcn_mfma_i32_16x16x64_i8(af4, bf0, acc[4][0], 0, 0, 0);
        acc[4][1] = __builtin_amdgcn_mfma_i32_16x16x64_i8(af4, bf1, acc[4][1], 0, 0, 0);
        acc[5][0] = __builtin_amdgcn_mfma_i32_16x16x64_i8(af5, bf0, acc[5][0], 0, 0, 0);
        acc[5][1] = __builtin_amdgcn_mfma_i32_16x16x64_i8(af5, bf1, acc[5][1], 0, 0, 0);
        acc[6][0] = __builtin_amdgcn_mfma_i32_16x16x64_i8(af6, bf0, acc[6][0], 0, 0, 0);
        acc[6][1] = __builtin_amdgcn_mfma_i32_16x16x64_i8(af6, bf1, acc[6][1], 0, 0, 0);
        acc[7][0] = __builtin_amdgcn_mfma_i32_16x16x64_i8(af7, bf0, acc[7][0], 0, 0, 0);
        acc[7][1] = __builtin_amdgcn_mfma_i32_16x16x64_i8(af7, bf1, acc[7][1], 0, 0, 0);
        __builtin_amdgcn_s_setprio(0);

        // step boundary: buf(s+1) landed; stage(s+2)'s 4 items stay in flight
        if (s + 2 < NSTEP)      { asm volatile("s_waitcnt vmcnt(4)" ::: "memory"); }
        else if (s + 1 < NSTEP) { asm volatile("s_waitcnt vmcnt(0)" ::: "memory"); }
        asm volatile("" ::: "memory");
        __builtin_amdgcn_s_barrier();
        cur = (cur >= 2) ? 0 : cur + 1;
    }

    // epilogue: C col = l&15 (co), row = (l>>4)*4 + reg (pixel)   [m89 layout]
#pragma unroll
    for (int cg = 0; cg < 2; ++cg) {
        const int co = co0 + v * 32 + cg * 16 + (l & 15);
        const float sc = scale[co], sh = shift[co];
#pragma unroll
        for (int pg = 0; pg < 8; ++pg) {
            const int prow0 = p0 + pg * 16 + (l >> 4) * 4;
#pragma unroll
            for (int rr = 0; rr < 4; ++rr) {
                const float y = (float)acc[pg][cg][rr];
                out[(size_t)(prow0 + rr) * COUT + co] = fmaxf(fmaf(y, sc, sh), 0.f);
            }
        }
    }
}

extern "C" void kernel_launch(void* const* d_in, const int* in_sizes, int n_in,
                              void* d_out, int out_size, void* d_ws, size_t ws_size,
                              hipStream_t stream)
{
    const float* x      = (const float*)d_in[0];
    const float* bias1  = (const float*)d_in[1];
    const float* kernel = (const float*)d_in[2];
    const float* bn_beta = (const float*)d_in[3];
    const float* bn_mean = (const float*)d_in[4];
    const float* bn_var  = (const float*)d_in[5];
    const float* bias2   = (const float*)d_in[6];
    float* out = (float*)d_out;

    signed char* pa  = (signed char*)d_ws;                // padded i8 image
    signed char* wtp = (signed char*)d_ws + WT_OFF;       // W_t[co][k]
    float* scale = (float*)((char*)d_ws + SC_OFF);
    float* shift = (float*)((char*)d_ws + SH_OFF);

    pack_a_kernel<<<dim3(NB * HP2 / 4), dim3(256), 0, stream>>>(x, bias1, pa);
    packw_kernel<<<dim3(KTOT / 64), dim3(256), 0, stream>>>(kernel, wtp);
    bnprep_kernel<<<dim3(1), dim3(256), 0, stream>>>(bn_beta, bn_mean, bn_var, bias2,
                                                     scale, shift);
    conv_mfma_kernel<<<dim3((NPIX / BM) * (COUT / BN)), dim3(256), 0, stream>>>(
        pa, wtp, scale, shift, out);
}

// Round 13
// 105.035 us; speedup vs baseline: 1.1810x; 1.1810x over previous
//
#include <hip/hip_runtime.h>

// Binarized conv block via i8 MFMA implicit GEMM.
//   a = sign(x+bias1) in {+1,-1} (i8), zero-padded image [32][58][58][256] i8
//   qk = sign(kernel) in {+1,-1} (i8), pre-transposed to W_t[co][k]
//   conv == GEMM: C[pixel][co] = sum_k A_im2col[pixel][k] * W[k][co]
//   out = relu(C*scale[co] + shift[co])   (folded BN + bias2)
// i8 zero-pad == true conv zero-pad -> exact integers, no edge corrections.
//
// R8-R12 ledger: all MFMA variants 22-27% MfmaUtil; stall = per-step sync with
// too little TLP (<=2 blocks/CU). R13: LDS = 32KB (2-deep, BM128xBN128) ->
// 4-5 blocks/CU; ONE phase per K-step (16-MFMA setprio cluster, 2 barriers);
// stage(s+1) at step top, vmcnt(0) drain at step end (issued ~500cyc earlier,
// cross-block waves cover the rest — m97/m114 regime). XCD-swizzled blockIdx
// (1568 = 8x196, bijective), pixel-major pairing so both co-halves of a pixel
// tile share an XCD L2 for the A-panel.

typedef int v4i __attribute__((ext_vector_type(4)));
typedef unsigned int u32;

#define NB   32
#define HW   56
#define HP   58
#define HP2  (HP*HP)             // 3364
#define CIN  256
#define COUT 256
#define NPIX (NB*HW*HW)          // 100352
#define KTOT 2304
#define BM   128                 // pixels per block
#define BN   128                 // couts per block
#define NSTEP 36                 // K steps of 64
#define NWG  ((NPIX/BM)*(COUT/BN))   // 1568 = 8*196

#define PA_BYTES ((size_t)NB*HP*HP*CIN)     // 27,557,888
#define WT_OFF   PA_BYTES
#define WT_BYTES ((size_t)KTOT*COUT)        // 589,824
#define SC_OFF   (WT_OFF + WT_BYTES)
#define SH_OFF   (SC_OFF + 1024)

__device__ __forceinline__ void g2l16(const void* g, void* l) {
    __builtin_amdgcn_global_load_lds(
        (const __attribute__((address_space(1))) void*)g,
        (__attribute__((address_space(3))) void*)l, 16, 0, 0);
}

// ------- pack activations incl. pad ring: sign(x+bias1) or 0 -> i8 -------
__global__ __launch_bounds__(256) void pack_a_kernel(
    const float* __restrict__ x, const float* __restrict__ b1,
    signed char* __restrict__ pa)
{
    const int lane = threadIdx.x & 63;
    const int pp = blockIdx.x * 4 + (threadIdx.x >> 6);   // padded pixel
    const int n = pp / HP2, r = pp % HP2, ph = r / HP, pw = r % HP;
    const int ci = lane * 4;
    u32 o = 0;
    if (ph >= 1 && ph <= HW && pw >= 1 && pw <= HW) {     // wave-uniform branch
        const int pix = (n * HW + ph - 1) * HW + (pw - 1);
        const float4 xv = *(const float4*)(x + (size_t)pix * CIN + ci);
        const float4 bv = *(const float4*)(b1 + ci);
        o  = (u32)(unsigned char)((xv.x + bv.x >= 0.f) ? 1 : -1);
        o |= (u32)(unsigned char)((xv.y + bv.y >= 0.f) ? 1 : -1) << 8;
        o |= (u32)(unsigned char)((xv.z + bv.z >= 0.f) ? 1 : -1) << 16;
        o |= (u32)(unsigned char)((xv.w + bv.w >= 0.f) ? 1 : -1) << 24;
    }
    *(u32*)(pa + (size_t)pp * CIN + ci) = o;
    // grid = NB*HP*HP/4 = 26912
}

// ---------------- pack + transpose weights: W_t[co][k] i8 ----------------
__global__ __launch_bounds__(256) void packw_kernel(
    const float* __restrict__ k, signed char* __restrict__ wt)
{
    __shared__ signed char tile[64][256];
    const int t = threadIdx.x, k0 = blockIdx.x * 64;
    for (int j = 0; j < 64; ++j)
        tile[j][t] = (k[(size_t)(k0 + j) * COUT + t] >= 0.f) ? 1 : -1;
    __syncthreads();
    u32 wd[16];
#pragma unroll
    for (int j = 0; j < 16; ++j) wd[j] = 0;
#pragma unroll
    for (int j = 0; j < 64; ++j)
        wd[j >> 2] |= ((u32)(unsigned char)tile[j][t]) << ((j & 3) * 8);
    uint4* dst = (uint4*)(wt + (size_t)t * KTOT + k0);
#pragma unroll
    for (int j = 0; j < 4; ++j)
        dst[j] = make_uint4(wd[4*j], wd[4*j+1], wd[4*j+2], wd[4*j+3]);
    // grid = KTOT/64 = 36
}

// ---------------- fold BN + bias2 ----------------
__global__ __launch_bounds__(256) void bnprep_kernel(
    const float* __restrict__ beta, const float* __restrict__ mean,
    const float* __restrict__ var, const float* __restrict__ b2,
    float* __restrict__ scale, float* __restrict__ shift)
{
    const int t = threadIdx.x;
    const float s = rsqrtf(var[t] + 1e-3f);
    scale[t] = s;
    shift[t] = beta[t] - mean[t] * s + b2[t];
}

// ---------------- i8 implicit-GEMM conv + BN + relu ----------------
// 256 thr (4 waves); block = 128 pixels x 128 couts; wave v owns all 128
// pixels x couts [v*32, v*32+32): acc[8][2], 16 mfma per K-step, one cluster.
__global__ __launch_bounds__(256, 4) void conv_mfma_kernel(
    const signed char* __restrict__ pa, const signed char* __restrict__ wt,
    const float* __restrict__ scale, const float* __restrict__ shift,
    float* __restrict__ out)
{
    __shared__ signed char Al[2][BM * 64];     // 2 x 8 KB
    __shared__ signed char Bl[2][BN * 64];     // 2 x 8 KB

    const int t = threadIdx.x, l = t & 63, v = t >> 6;
    // XCD swizzle (1568 = 8 x 196, bijective): consecutive swz on same XCD
    const int swz  = (blockIdx.x & 7) * (NWG / 8) + (blockIdx.x >> 3);
    const int tile = swz >> 1;
    const int co0  = (swz & 1) << 7;           // co-halves of a tile adjacent
    const int p0 = tile * BM;

    // A staging: thread t stages chunk (t&3) of pixels q and q+64 (q = t>>2)
    const signed char* abase[2];
#pragma unroll
    for (int i = 0; i < 2; ++i) {
        const int q = (t >> 2) + i * 64;
        const int p = p0 + q;
        const int n = p / 3136, r = p % 3136, h = r / 56, w = r % 56;
        const int aswz = (((t & 3) ^ ((q >> 1) & 3)) << 4);  // source pre-swizzle
        abase[i] = pa + ((size_t)(n * HP + h) * HP + w) * CIN + aswz;
    }

    // B staging: call j stages LDS row r = v*32 + j*16 + l/4, chunk l&3
    const signed char* wbase[2];
#pragma unroll
    for (int j = 0; j < 2; ++j) {
        const int r = v * 32 + j * 16 + (l >> 2);
        const int bswz = (((l & 3) ^ ((r >> 1) & 3)) << 4);
        wbase[j] = wt + (size_t)(co0 + r) * KTOT + bswz;
    }

    // fragment ds_read byte offsets (swizzled reads match pre-swizzled src)
    int aoff[8], boff[2];
#pragma unroll
    for (int pg = 0; pg < 8; ++pg) {
        const int row = pg * 16 + (l & 15);
        aoff[pg] = row * 64 + ((((l >> 4) ^ (row >> 1)) & 3) << 4);
    }
#pragma unroll
    for (int cg = 0; cg < 2; ++cg) {
        const int row = v * 32 + cg * 16 + (l & 15);
        boff[cg] = row * 64 + ((((l >> 4) ^ (row >> 1)) & 3) << 4);
    }

    v4i acc[8][2];
#pragma unroll
    for (int i = 0; i < 8; ++i)
#pragma unroll
        for (int j = 0; j < 2; ++j) acc[i][j] = (v4i){0, 0, 0, 0};

    auto goffA = [&](int s) {
        const int tap = s >> 2, cq = s & 3;
        const int ty = tap / 3, tx = tap - ty * 3;
        return ((ty * HP + tx) << 8) + (cq << 6);
    };
    auto STAGE = [&](int buf, int s) {         // 4 vm-items per thread
        const int go = goffA(s);
        g2l16(abase[0] + go, &Al[buf][v * 1024]);
        g2l16(abase[1] + go, &Al[buf][4096 + v * 1024]);
        g2l16(wbase[0] + (s << 6), &Bl[buf][v * 2048]);
        g2l16(wbase[1] + (s << 6), &Bl[buf][v * 2048 + 1024]);
    };

    // prologue
    STAGE(0, 0);
    asm volatile("s_waitcnt vmcnt(0)" ::: "memory");
    __builtin_amdgcn_s_barrier();

#pragma unroll 1
    for (int s = 0; s < NSTEP; ++s) {
        const int cur = s & 1, nxt = cur ^ 1;
        signed char* Ac = &Al[0][0] + cur * (BM * 64);
        signed char* Bc = &Bl[0][0] + cur * (BN * 64);
        if (s + 1 < NSTEP) STAGE(nxt, s + 1);  // issue early; lands by step end
        // read all fragments of cur (compiler inserts lgkmcnt before MFMA)
        v4i bf0 = *(const v4i*)(Bc + boff[0]);
        v4i bf1 = *(const v4i*)(Bc + boff[1]);
        v4i af0 = *(const v4i*)(Ac + aoff[0]);
        v4i af1 = *(const v4i*)(Ac + aoff[1]);
        v4i af2 = *(const v4i*)(Ac + aoff[2]);
        v4i af3 = *(const v4i*)(Ac + aoff[3]);
        v4i af4 = *(const v4i*)(Ac + aoff[4]);
        v4i af5 = *(const v4i*)(Ac + aoff[5]);
        v4i af6 = *(const v4i*)(Ac + aoff[6]);
        v4i af7 = *(const v4i*)(Ac + aoff[7]);
        __builtin_amdgcn_s_setprio(1);
        acc[0][0] = __builtin_amdgcn_mfma_i32_16x16x64_i8(af0, bf0, acc[0][0], 0, 0, 0);
        acc[0][1] = __builtin_amdgcn_mfma_i32_16x16x64_i8(af0, bf1, acc[0][1], 0, 0, 0);
        acc[1][0] = __builtin_amdgcn_mfma_i32_16x16x64_i8(af1, bf0, acc[1][0], 0, 0, 0);
        acc[1][1] = __builtin_amdgcn_mfma_i32_16x16x64_i8(af1, bf1, acc[1][1], 0, 0, 0);
        acc[2][0] = __builtin_amdgcn_mfma_i32_16x16x64_i8(af2, bf0, acc[2][0], 0, 0, 0);
        acc[2][1] = __builtin_amdgcn_mfma_i32_16x16x64_i8(af2, bf1, acc[2][1], 0, 0, 0);
        acc[3][0] = __builtin_amdgcn_mfma_i32_16x16x64_i8(af3, bf0, acc[3][0], 0, 0, 0);
        acc[3][1] = __builtin_amdgcn_mfma_i32_16x16x64_i8(af3, bf1, acc[3][1], 0, 0, 0);
        acc[4][0] = __builtin_amdgcn_mfma_i32_16x16x64_i8(af4, bf0, acc[4][0], 0, 0, 0);
        acc[4][1] = __builtin_amdgcn_mfma_i32_16x16x64_i8(af4, bf1, acc[4][1], 0, 0, 0);
        acc[5][0] = __builtin_amdgcn_mfma_i32_16x16x64_i8(af5, bf0, acc[5][0], 0, 0, 0);
        acc[5][1] = __builtin_amdgcn_mfma_i32_16x16x64_i8(af5, bf1, acc[5][1], 0, 0, 0);
        acc[6][0] = __builtin_amdgcn_mfma_i32_16x16x64_i8(af6, bf0, acc[6][0], 0, 0, 0);
        acc[6][1] = __builtin_amdgcn_mfma_i32_16x16x64_i8(af6, bf1, acc[6][1], 0, 0, 0);
        acc[7][0] = __builtin_amdgcn_mfma_i32_16x16x64_i8(af7, bf0, acc[7][0], 0, 0, 0);
        acc[7][1] = __builtin_amdgcn_mfma_i32_16x16x64_i8(af7, bf1, acc[7][1], 0, 0, 0);
        __builtin_amdgcn_s_setprio(0);
        // stage(s+1) landed + everyone done reading cur (reads precede MFMAs)
        asm volatile("s_waitcnt vmcnt(0)" ::: "memory");
        __builtin_amdgcn_s_barrier();
    }

    // epilogue: C col = l&15 (co), row = (l>>4)*4 + reg (pixel)   [m89 layout]
#pragma unroll
    for (int cg = 0; cg < 2; ++cg) {
        const int co = co0 + v * 32 + cg * 16 + (l & 15);
        const float sc = scale[co], sh = shift[co];
#pragma unroll
        for (int pg = 0; pg < 8; ++pg) {
            const int prow0 = p0 + pg * 16 + (l >> 4) * 4;
#pragma unroll
            for (int rr = 0; rr < 4; ++rr) {
                const float y = (float)acc[pg][cg][rr];
                out[(size_t)(prow0 + rr) * COUT + co] = fmaxf(fmaf(y, sc, sh), 0.f);
            }
        }
    }
}

extern "C" void kernel_launch(void* const* d_in, const int* in_sizes, int n_in,
                              void* d_out, int out_size, void* d_ws, size_t ws_size,
                              hipStream_t stream)
{
    const float* x      = (const float*)d_in[0];
    const float* bias1  = (const float*)d_in[1];
    const float* kernel = (const float*)d_in[2];
    const float* bn_beta = (const float*)d_in[3];
    const float* bn_mean = (const float*)d_in[4];
    const float* bn_var  = (const float*)d_in[5];
    const float* bias2   = (const float*)d_in[6];
    float* out = (float*)d_out;

    signed char* pa  = (signed char*)d_ws;                // padded i8 image
    signed char* wtp = (signed char*)d_ws + WT_OFF;       // W_t[co][k]
    float* scale = (float*)((char*)d_ws + SC_OFF);
    float* shift = (float*)((char*)d_ws + SH_OFF);

    pack_a_kernel<<<dim3(NB * HP2 / 4), dim3(256), 0, stream>>>(x, bias1, pa);
    packw_kernel<<<dim3(KTOT / 64), dim3(256), 0, stream>>>(kernel, wtp);
    bnprep_kernel<<<dim3(1), dim3(256), 0, stream>>>(bn_beta, bn_mean, bn_var, bias2,
                                                     scale, shift);
    conv_mfma_kernel<<<dim3(NWG), dim3(256), 0, stream>>>(pa, wtp, scale, shift, out);
}

// Round 14
// 102.946 us; speedup vs baseline: 1.2050x; 1.0203x over previous
//
#include <hip/hip_runtime.h>

// Binarized conv block via i8 MFMA implicit GEMM.
//   a = sign(x+bias1) in {+1,-1} (i8), zero-padded image [32][58][58][256] i8
//   qk = sign(kernel) in {+1,-1} (i8), pre-transposed to W_t[co][k]
//   conv == GEMM: C[pixel][co] = sum_k A_im2col[pixel][k] * W[k][co]
//   out = relu(C*scale[co] + shift[co])   (folded BN + bias2)
// i8 zero-pad == true conv zero-pad -> exact integers, no edge corrections.
//
// R13 ledger: conv 87.6us @ MfmaUtil 29%. New accounting: per-CU LDS-read
// volume (each wave reads the whole A-tile) = 2.26GB total ~ 43us/CU of
// ds_read pipe — co-bottleneck with the 30us MFMA floor. R14:
//  (1) 2x2 wave grid (wave owns 64px x 64co, acc[4][4]) — fragment traffic
//      minimized: volume prop. to (wn*BM + wm*BN), 40->32KB/block-step.
//  (2) BK=128 (NSTEP=18): halves barrier/vmcnt events, 32-MFMA clusters.
//  (3) unchanged: stage-early + one vmcnt(0)+barrier per step, setprio,
//      XCD swizzle (1568 = 8x196), chunk-XOR swizzle on staging source.

typedef int v4i __attribute__((ext_vector_type(4)));
typedef unsigned int u32;

#define NB   32
#define HW   56
#define HP   58
#define HP2  (HP*HP)             // 3364
#define CIN  256
#define COUT 256
#define NPIX (NB*HW*HW)          // 100352
#define KTOT 2304
#define BM   128                 // pixels per block
#define BN   128                 // couts per block
#define NSTEP 18                 // K steps of 128 (2 x 64-chunks)
#define NWG  ((NPIX/BM)*(COUT/BN))   // 1568 = 8*196

#define PA_BYTES ((size_t)NB*HP*HP*CIN)     // 27,557,888
#define WT_OFF   PA_BYTES
#define WT_BYTES ((size_t)KTOT*COUT)        // 589,824
#define SC_OFF   (WT_OFF + WT_BYTES)
#define SH_OFF   (SC_OFF + 1024)

__device__ __forceinline__ void g2l16(const void* g, void* l) {
    __builtin_amdgcn_global_load_lds(
        (const __attribute__((address_space(1))) void*)g,
        (__attribute__((address_space(3))) void*)l, 16, 0, 0);
}

// ------- pack activations incl. pad ring: sign(x+bias1) or 0 -> i8 -------
__global__ __launch_bounds__(256) void pack_a_kernel(
    const float* __restrict__ x, const float* __restrict__ b1,
    signed char* __restrict__ pa)
{
    const int lane = threadIdx.x & 63;
    const int pp = blockIdx.x * 4 + (threadIdx.x >> 6);   // padded pixel
    const int n = pp / HP2, r = pp % HP2, ph = r / HP, pw = r % HP;
    const int ci = lane * 4;
    u32 o = 0;
    if (ph >= 1 && ph <= HW && pw >= 1 && pw <= HW) {     // wave-uniform branch
        const int pix = (n * HW + ph - 1) * HW + (pw - 1);
        const float4 xv = *(const float4*)(x + (size_t)pix * CIN + ci);
        const float4 bv = *(const float4*)(b1 + ci);
        o  = (u32)(unsigned char)((xv.x + bv.x >= 0.f) ? 1 : -1);
        o |= (u32)(unsigned char)((xv.y + bv.y >= 0.f) ? 1 : -1) << 8;
        o |= (u32)(unsigned char)((xv.z + bv.z >= 0.f) ? 1 : -1) << 16;
        o |= (u32)(unsigned char)((xv.w + bv.w >= 0.f) ? 1 : -1) << 24;
    }
    *(u32*)(pa + (size_t)pp * CIN + ci) = o;
    // grid = NB*HP*HP/4 = 26912
}

// ---------------- pack + transpose weights: W_t[co][k] i8 ----------------
__global__ __launch_bounds__(256) void packw_kernel(
    const float* __restrict__ k, signed char* __restrict__ wt)
{
    __shared__ signed char tile[64][256];
    const int t = threadIdx.x, k0 = blockIdx.x * 64;
    for (int j = 0; j < 64; ++j)
        tile[j][t] = (k[(size_t)(k0 + j) * COUT + t] >= 0.f) ? 1 : -1;
    __syncthreads();
    u32 wd[16];
#pragma unroll
    for (int j = 0; j < 16; ++j) wd[j] = 0;
#pragma unroll
    for (int j = 0; j < 64; ++j)
        wd[j >> 2] |= ((u32)(unsigned char)tile[j][t]) << ((j & 3) * 8);
    uint4* dst = (uint4*)(wt + (size_t)t * KTOT + k0);
#pragma unroll
    for (int j = 0; j < 4; ++j)
        dst[j] = make_uint4(wd[4*j], wd[4*j+1], wd[4*j+2], wd[4*j+3]);
    // grid = KTOT/64 = 36
}

// ---------------- fold BN + bias2 ----------------
__global__ __launch_bounds__(256) void bnprep_kernel(
    const float* __restrict__ beta, const float* __restrict__ mean,
    const float* __restrict__ var, const float* __restrict__ b2,
    float* __restrict__ scale, float* __restrict__ shift)
{
    const int t = threadIdx.x;
    const float s = rsqrtf(var[t] + 1e-3f);
    scale[t] = s;
    shift[t] = beta[t] - mean[t] * s + b2[t];
}

// ---------------- i8 implicit-GEMM conv + BN + relu ----------------
// 256 thr = 2x2 wave grid; block = 128px x 128co; wave (vm,vn) owns
// 64px x 64co: acc[4][4], 32 mfma_i32_16x16x64_i8 per K-step of 128.
__global__ __launch_bounds__(256, 2) void conv_mfma_kernel(
    const signed char* __restrict__ pa, const signed char* __restrict__ wt,
    const float* __restrict__ scale, const float* __restrict__ shift,
    float* __restrict__ out)
{
    // per buffer: A = 2ksub x 128px x 64B (16KB), B = 2ksub x 128co x 64B (16KB)
    __shared__ signed char L[2][32768];

    const int t = threadIdx.x, l = t & 63, v = t >> 6;
    const int vm = v >> 1, vn = v & 1;
    // XCD swizzle (1568 = 8 x 196, bijective); co-halves of a tile adjacent
    const int swz  = (blockIdx.x & 7) * (NWG / 8) + (blockIdx.x >> 3);
    const int tile = swz >> 1;
    const int co0  = (swz & 1) << 7;
    const int p0 = tile * BM;

    // A staging: thread t stages 16B slot (t&3) of pixel q=(t>>2)+i*64
    const signed char* abase[2];
#pragma unroll
    for (int i = 0; i < 2; ++i) {
        const int q = (t >> 2) + i * 64;
        const int p = p0 + q;
        const int n = p / 3136, r = p % 3136, h = r / 56, w = r % 56;
        const int aswz = (((t & 3) ^ ((q >> 1) & 3)) << 4);  // source pre-swizzle
        abase[i] = pa + ((size_t)(n * HP + h) * HP + w) * CIN + aswz;
    }
    // B staging: thread t stages slot (t&3) of W-row r=(t>>2)+j*64
    const signed char* wbase[2];
#pragma unroll
    for (int j = 0; j < 2; ++j) {
        const int r = j * 64 + (t >> 2);
        const int bswz = (((t & 3) ^ ((r >> 1) & 3)) << 4);
        wbase[j] = wt + (size_t)(co0 + r) * KTOT + bswz;
    }

    // fragment ds_read byte offsets (swizzled reads match pre-swizzled src)
    int aoff[4], boff[4];
#pragma unroll
    for (int pg = 0; pg < 4; ++pg) {
        const int row = vm * 64 + pg * 16 + (l & 15);
        aoff[pg] = row * 64 + ((((l >> 4) ^ (row >> 1)) & 3) << 4);
    }
#pragma unroll
    for (int cg = 0; cg < 4; ++cg) {
        const int row = vn * 64 + cg * 16 + (l & 15);
        boff[cg] = 16384 + row * 64 + ((((l >> 4) ^ (row >> 1)) & 3) << 4);
    }

    v4i acc[4][4];
#pragma unroll
    for (int i = 0; i < 4; ++i)
#pragma unroll
        for (int j = 0; j < 4; ++j) acc[i][j] = (v4i){0, 0, 0, 0};

    auto goffA = [&](int k64) {
        const int tap = k64 >> 2, cq = k64 & 3;
        const int ty = tap / 3, tx = tap - ty * 3;
        return ((ty * HP + tx) << 8) + (cq << 6);
    };
    auto STAGE = [&](int buf, int s) {         // 8 g2l16 per thread
#pragma unroll
        for (int ks = 0; ks < 2; ++ks) {
            const int k64 = 2 * s + ks;
            const int go = goffA(k64);
            g2l16(abase[0] + go, &L[buf][ks * 8192 + v * 1024]);
            g2l16(abase[1] + go, &L[buf][ks * 8192 + 4096 + v * 1024]);
            g2l16(wbase[0] + (k64 << 6), &L[buf][16384 + ks * 8192 + v * 1024]);
            g2l16(wbase[1] + (k64 << 6), &L[buf][16384 + ks * 8192 + 4096 + v * 1024]);
        }
    };

    // prologue
    STAGE(0, 0);
    asm volatile("s_waitcnt vmcnt(0)" ::: "memory");
    __builtin_amdgcn_s_barrier();

#pragma unroll 1
    for (int s = 0; s < NSTEP; ++s) {
        const int cur = s & 1, nxt = cur ^ 1;
        const signed char* Lc = &L[cur][0];
        if (s + 1 < NSTEP) STAGE(nxt, s + 1);  // issue early; lands by step end
        // read all fragments of cur (compiler inserts lgkmcnt before MFMA)
        v4i af[2][4], bf[2][4];
#pragma unroll
        for (int ks = 0; ks < 2; ++ks) {
#pragma unroll
            for (int pg = 0; pg < 4; ++pg)
                af[ks][pg] = *(const v4i*)(Lc + ks * 8192 + aoff[pg]);
#pragma unroll
            for (int cg = 0; cg < 4; ++cg)
                bf[ks][cg] = *(const v4i*)(Lc + ks * 8192 + boff[cg]);
        }
        __builtin_amdgcn_s_setprio(1);
#pragma unroll
        for (int ks = 0; ks < 2; ++ks)
#pragma unroll
            for (int pg = 0; pg < 4; ++pg)
#pragma unroll
                for (int cg = 0; cg < 4; ++cg)
                    acc[pg][cg] = __builtin_amdgcn_mfma_i32_16x16x64_i8(
                        af[ks][pg], bf[ks][cg], acc[pg][cg], 0, 0, 0);
        __builtin_amdgcn_s_setprio(0);
        // stage(s+1) landed + all waves done reading cur (reads precede MFMAs)
        asm volatile("s_waitcnt vmcnt(0)" ::: "memory");
        __builtin_amdgcn_s_barrier();
    }

    // epilogue: C col = l&15 (co), row = (l>>4)*4 + reg (pixel)   [m89 layout]
#pragma unroll
    for (int cg = 0; cg < 4; ++cg) {
        const int co = co0 + vn * 64 + cg * 16 + (l & 15);
        const float sc = scale[co], sh = shift[co];
#pragma unroll
        for (int pg = 0; pg < 4; ++pg) {
            const int prow0 = p0 + vm * 64 + pg * 16 + (l >> 4) * 4;
#pragma unroll
            for (int rr = 0; rr < 4; ++rr) {
                const float y = (float)acc[pg][cg][rr];
                out[(size_t)(prow0 + rr) * COUT + co] = fmaxf(fmaf(y, sc, sh), 0.f);
            }
        }
    }
}

extern "C" void kernel_launch(void* const* d_in, const int* in_sizes, int n_in,
                              void* d_out, int out_size, void* d_ws, size_t ws_size,
                              hipStream_t stream)
{
    const float* x      = (const float*)d_in[0];
    const float* bias1  = (const float*)d_in[1];
    const float* kernel = (const float*)d_in[2];
    const float* bn_beta = (const float*)d_in[3];
    const float* bn_mean = (const float*)d_in[4];
    const float* bn_var  = (const float*)d_in[5];
    const float* bias2   = (const float*)d_in[6];
    float* out = (float*)d_out;

    signed char* pa  = (signed char*)d_ws;                // padded i8 image
    signed char* wtp = (signed char*)d_ws + WT_OFF;       // W_t[co][k]
    float* scale = (float*)((char*)d_ws + SC_OFF);
    float* shift = (float*)((char*)d_ws + SH_OFF);

    pack_a_kernel<<<dim3(NB * HP2 / 4), dim3(256), 0, stream>>>(x, bias1, pa);
    packw_kernel<<<dim3(KTOT / 64), dim3(256), 0, stream>>>(kernel, wtp);
    bnprep_kernel<<<dim3(1), dim3(256), 0, stream>>>(bn_beta, bn_mean, bn_var, bias2,
                                                     scale, shift);
    conv_mfma_kernel<<<dim3(NWG), dim3(256), 0, stream>>>(pa, wtp, scale, shift, out);
}